// Round 1
// baseline (767.244 us; speedup 1.0000x reference)
//
#include <hip/hip_runtime.h>

#define IN_F   128
#define H_HEADS 4
#define OUTD   64
#define HOUT   256      // H*OUT
#define TOTC   576      // HOUT (fc) + HOUT (gat_res) + OUTD (res)
#define NEG_SLOPE 0.2f
#define BN_EPS 1e-5f

// ---------------- pack weights into one [128 x 576] B matrix ----------------
__global__ void pack_b_kernel(const float* __restrict__ Wfc,
                              const float* __restrict__ Wres,
                              const float* __restrict__ Wout,
                              float* __restrict__ Bc) {
    int i = blockIdx.x * 256 + threadIdx.x;
    if (i >= IN_F * TOTC) return;
    int k = i / TOTC, c = i % TOTC;
    float v;
    if (c < HOUT)            v = Wfc[k * HOUT + c];
    else if (c < 2 * HOUT)   v = Wres[k * HOUT + (c - HOUT)];
    else                     v = Wout[k * OUTD + (c - 2 * HOUT)];
    Bc[i] = v;
}

// ---------------- fp32 tiled GEMM: [N x 128] @ [128 x 576] -> HW ----------------
__global__ __launch_bounds__(256) void gemm_kernel(const float* __restrict__ A,
                                                   const float* __restrict__ B,
                                                   float* __restrict__ C, int N) {
    __shared__ float As[64][132];   // pad 132: 4-row stride -> 2-way bank alias (free)
    __shared__ float Bs[128][64];
    int m0 = blockIdx.x * 64;
    int n0 = blockIdx.y * 64;
    int t = threadIdx.x;

    // Load A tile (64 x 128) as float4
    for (int i = 0; i < 8; ++i) {
        int slot = t + i * 256;          // 0 .. 2047
        int r = slot >> 5;               // /32 float4-per-row
        int c4 = (slot & 31) << 2;
        float4 v = make_float4(0.f, 0.f, 0.f, 0.f);
        if (m0 + r < N) v = *(const float4*)(A + (size_t)(m0 + r) * IN_F + c4);
        *(float4*)(&As[r][c4]) = v;
    }
    // Load B tile (128 x 64) as float4
    for (int i = 0; i < 8; ++i) {
        int slot = t + i * 256;          // 0 .. 2047
        int r = slot >> 4;               // /16 float4-per-row
        int c4 = (slot & 15) << 2;
        *(float4*)(&Bs[r][c4]) = *(const float4*)(B + (size_t)r * TOTC + n0 + c4);
    }
    __syncthreads();

    int tm = t >> 4, tn = t & 15;
    float acc[4][4] = {};
    for (int k = 0; k < IN_F; k += 4) {
        float4 a[4], b[4];
#pragma unroll
        for (int i = 0; i < 4; ++i) a[i] = *(const float4*)(&As[tm * 4 + i][k]);
#pragma unroll
        for (int kk = 0; kk < 4; ++kk) b[kk] = *(const float4*)(&Bs[k + kk][tn * 4]);
#pragma unroll
        for (int i = 0; i < 4; ++i) {
            float ax = a[i].x, ay = a[i].y, az = a[i].z, aw = a[i].w;
            acc[i][0] += ax * b[0].x + ay * b[1].x + az * b[2].x + aw * b[3].x;
            acc[i][1] += ax * b[0].y + ay * b[1].y + az * b[2].y + aw * b[3].y;
            acc[i][2] += ax * b[0].z + ay * b[1].z + az * b[2].z + aw * b[3].z;
            acc[i][3] += ax * b[0].w + ay * b[1].w + az * b[2].w + aw * b[3].w;
        }
    }
#pragma unroll
    for (int i = 0; i < 4; ++i) {
        int r = m0 + tm * 4 + i;
        if (r < N)
            *(float4*)(C + (size_t)r * TOTC + n0 + tn * 4) =
                make_float4(acc[i][0], acc[i][1], acc[i][2], acc[i][3]);
    }
}

// ---------------- per-node attention logits el/er ----------------
__global__ __launch_bounds__(256) void elr_kernel(const float* __restrict__ HW,
                                                  const float* __restrict__ attn_l,
                                                  const float* __restrict__ attn_r,
                                                  float* __restrict__ el,
                                                  float* __restrict__ er, int N) {
    int wave = threadIdx.x >> 6;
    int lane = threadIdx.x & 63;
    int v = blockIdx.x * 4 + wave;
    if (v >= N) return;
    float pl[4], pr[4];
#pragma unroll
    for (int hd = 0; hd < 4; ++hd) {
        float hv = HW[(size_t)v * TOTC + hd * 64 + lane];
        pl[hd] = hv * attn_l[hd * 64 + lane];
        pr[hd] = hv * attn_r[hd * 64 + lane];
    }
#pragma unroll
    for (int off = 32; off; off >>= 1) {
#pragma unroll
        for (int hd = 0; hd < 4; ++hd) {
            pl[hd] += __shfl_down(pl[hd], off);
            pr[hd] += __shfl_down(pr[hd], off);
        }
    }
    if (lane == 0) {
        *(float4*)(el + (size_t)v * 4) = make_float4(pl[0], pl[1], pl[2], pl[3]);
        *(float4*)(er + (size_t)v * 4) = make_float4(pr[0], pr[1], pr[2], pr[3]);
    }
}

// ---------------- edge scores: s = exp(leaky(el[src]+er[dst])), ssum, degree ----------------
__global__ void edge_score_kernel(const int* __restrict__ src, const int* __restrict__ dst,
                                  const float* __restrict__ el, const float* __restrict__ er,
                                  float* __restrict__ s, float* __restrict__ ssum,
                                  int* __restrict__ degree, int E) {
    int e = blockIdx.x * blockDim.x + threadIdx.x;
    if (e >= E) return;
    int u = src[e], v = dst[e];
    float4 l = *(const float4*)(el + (size_t)u * 4);
    float4 r = *(const float4*)(er + (size_t)v * 4);
    float4 sc;
    float x;
    x = l.x + r.x; x = x > 0.f ? x : NEG_SLOPE * x; sc.x = expf(x);
    x = l.y + r.y; x = x > 0.f ? x : NEG_SLOPE * x; sc.y = expf(x);
    x = l.z + r.z; x = x > 0.f ? x : NEG_SLOPE * x; sc.z = expf(x);
    x = l.w + r.w; x = x > 0.f ? x : NEG_SLOPE * x; sc.w = expf(x);
    *(float4*)(s + (size_t)e * 4) = sc;
    atomicAdd(ssum + (size_t)v * 4 + 0, sc.x);
    atomicAdd(ssum + (size_t)v * 4 + 1, sc.y);
    atomicAdd(ssum + (size_t)v * 4 + 2, sc.z);
    atomicAdd(ssum + (size_t)v * 4 + 3, sc.w);
    atomicAdd(degree + v, 1);
}

// ---------------- single-block exclusive scan of degree -> offsets, cursor ----------------
__global__ __launch_bounds__(1024) void scan_kernel(const int* __restrict__ degree,
                                                    int* __restrict__ offsets,
                                                    int* __restrict__ cursor, int N) {
    __shared__ int sm[1024];
    int t = threadIdx.x;
    int chunk = (N + 1023) / 1024;
    int begin = t * chunk;
    int end = begin + chunk; if (end > N) end = N; if (begin > N) begin = N;
    int local = 0;
    for (int i = begin; i < end; ++i) local += degree[i];
    sm[t] = local;
    __syncthreads();
    for (int off = 1; off < 1024; off <<= 1) {
        int val = (t >= off) ? sm[t - off] : 0;
        __syncthreads();
        sm[t] += val;
        __syncthreads();
    }
    int run = sm[t] - local;  // exclusive prefix of this chunk
    for (int i = begin; i < end; ++i) {
        offsets[i] = run;
        cursor[i] = run;
        run += degree[i];
    }
    if (t == 1023) offsets[N] = sm[1023];
}

// ---------------- scatter edge ids into CSR order ----------------
__global__ void scatter_kernel(const int* __restrict__ dst, int* __restrict__ cursor,
                               int* __restrict__ edge_ids, int E) {
    int e = blockIdx.x * blockDim.x + threadIdx.x;
    if (e >= E) return;
    int p = atomicAdd(cursor + dst[e], 1);
    edge_ids[p] = e;
}

// ---------------- aggregation + epilogue: one wave per dst node ----------------
__global__ __launch_bounds__(64) void agg_kernel(const float* __restrict__ HW,
                                                 const float* __restrict__ s,
                                                 const float* __restrict__ ssum,
                                                 const int* __restrict__ offsets,
                                                 const int* __restrict__ edge_ids,
                                                 const int* __restrict__ src,
                                                 const float* __restrict__ gat_bias,
                                                 const float* __restrict__ conv_w,
                                                 const float* __restrict__ conv_b,
                                                 const float* __restrict__ res_b,
                                                 float* __restrict__ y, int N) {
    int v = blockIdx.x;
    int lane = threadIdx.x;
    float4 sv = *(const float4*)(ssum + (size_t)v * 4);
    float4 rc = make_float4(1.f / (sv.x + 1e-16f), 1.f / (sv.y + 1e-16f),
                            1.f / (sv.z + 1e-16f), 1.f / (sv.w + 1e-16f));
    int b = offsets[v], e2 = offsets[v + 1];
    float acc0 = 0.f, acc1 = 0.f, acc2 = 0.f, acc3 = 0.f;
    for (int i = b; i < e2; ++i) {
        int eid = edge_ids[i];
        int u = src[eid];
        float4 sc = *(const float4*)(s + (size_t)eid * 4);
        const float* hp = HW + (size_t)u * TOTC + lane;
        acc0 += (sc.x * rc.x) * hp[0];
        acc1 += (sc.y * rc.y) * hp[64];
        acc2 += (sc.z * rc.z) * hp[128];
        acc3 += (sc.w * rc.w) * hp[192];
    }
    const float* hv = HW + (size_t)v * TOTC;
    float accs[4] = {acc0, acc1, acc2, acc3};
    float yv = conv_b[0];
#pragma unroll
    for (int hd = 0; hd < 4; ++hd) {
        float r = accs[hd] + hv[HOUT + hd * 64 + lane] + gat_bias[hd * 64 + lane];
        r = r > 0.f ? r : 0.f;
        yv += conv_w[hd] * r;
    }
    float resv = hv[2 * HOUT + lane] + res_b[lane];
    yv += resv > 0.f ? resv : 0.f;
    y[(size_t)v * 64 + lane] = yv;
}

// ---------------- BN: block-partial sums then finalize then normalize ----------------
__global__ __launch_bounds__(256) void bn_partial_kernel(const float* __restrict__ y,
                                                         float* __restrict__ bnsum,
                                                         float* __restrict__ bnsumsq, int total) {
    __shared__ float smem[256];
    int t = threadIdx.x;
    size_t idx = (size_t)blockIdx.x * 256 + t;
    size_t stride = (size_t)gridDim.x * 256;   // multiple of 64 -> d fixed per thread
    float sum = 0.f, sq = 0.f;
    for (; idx < (size_t)total; idx += stride) {
        float v = y[idx];
        sum += v; sq += v * v;
    }
    int d = t & 63;
    smem[t] = sum; __syncthreads();
    if (t < 64) {
        float a = smem[t] + smem[t + 64] + smem[t + 128] + smem[t + 192];
        atomicAdd(bnsum + d, a);
    }
    __syncthreads();
    smem[t] = sq; __syncthreads();
    if (t < 64) {
        float a = smem[t] + smem[t + 64] + smem[t + 128] + smem[t + 192];
        atomicAdd(bnsumsq + d, a);
    }
}

__global__ void bn_final_kernel(const float* __restrict__ bnsum, const float* __restrict__ bnsumsq,
                                const float* __restrict__ gamma, const float* __restrict__ beta,
                                float* __restrict__ scale, float* __restrict__ shift, int N) {
    int d = threadIdx.x;
    if (d >= 64) return;
    float invN = 1.f / (float)N;
    float mean = bnsum[d] * invN;
    float var = bnsumsq[d] * invN - mean * mean;
    float sc = gamma[d] * rsqrtf(var + BN_EPS);
    scale[d] = sc;
    shift[d] = beta[d] - mean * sc;
}

__global__ void norm_kernel(const float* __restrict__ y, const float* __restrict__ scale,
                            const float* __restrict__ shift, float* __restrict__ out, int total4) {
    int idx = blockIdx.x * blockDim.x + threadIdx.x;
    if (idx >= total4) return;
    float4 v = *(const float4*)(y + (size_t)idx * 4);
    int d = (idx * 4) & 63;
    float4 o;
    o.x = v.x * scale[d + 0] + shift[d + 0];
    o.y = v.y * scale[d + 1] + shift[d + 1];
    o.z = v.z * scale[d + 2] + shift[d + 2];
    o.w = v.w * scale[d + 3] + shift[d + 3];
    *(float4*)(out + (size_t)idx * 4) = o;
}

// ---------------- launch ----------------
extern "C" void kernel_launch(void* const* d_in, const int* in_sizes, int n_in,
                              void* d_out, int out_size, void* d_ws, size_t ws_size,
                              hipStream_t stream) {
    const float* node_feats = (const float*)d_in[0];
    const float* W_fc       = (const float*)d_in[1];
    const float* attn_l     = (const float*)d_in[2];
    const float* attn_r     = (const float*)d_in[3];
    const float* gat_res_w  = (const float*)d_in[4];
    const float* gat_bias   = (const float*)d_in[5];
    const float* conv_w     = (const float*)d_in[6];
    const float* conv_b     = (const float*)d_in[7];
    const float* res_w      = (const float*)d_in[8];
    const float* res_b      = (const float*)d_in[9];
    const float* bn_gamma   = (const float*)d_in[10];
    const float* bn_beta    = (const float*)d_in[11];
    const int*   src        = (const int*)d_in[12];
    const int*   dst        = (const int*)d_in[13];

    const int N = in_sizes[0] / IN_F;
    const int E = in_sizes[12];

    char* ws = (char*)d_ws;
    size_t off = 0;
    auto alloc = [&](size_t bytes) -> void* {
        void* p = (void*)(ws + off);
        off += (bytes + 255) & ~(size_t)255;
        return p;
    };

    // --- zero zone (memset once) ---
    int*   degree  = (int*)alloc((size_t)N * 4);
    float* ssum    = (float*)alloc((size_t)N * 4 * 4);
    float* bnsum   = (float*)alloc(64 * 4);
    float* bnsumsq = (float*)alloc(64 * 4);
    size_t zero_bytes = off;
    // --- rest ---
    float* Bc       = (float*)alloc((size_t)IN_F * TOTC * 4);
    float* HW       = (float*)alloc((size_t)N * TOTC * 4);
    float* el       = (float*)alloc((size_t)N * 4 * 4);
    float* er       = (float*)alloc((size_t)N * 4 * 4);
    float* s        = (float*)alloc((size_t)E * 4 * 4);
    int*   offsets  = (int*)alloc((size_t)(N + 1) * 4);
    int*   cursor   = (int*)alloc((size_t)N * 4);
    int*   edge_ids = (int*)alloc((size_t)E * 4);
    float* y        = (float*)alloc((size_t)N * OUTD * 4);
    float* scale    = (float*)alloc(64 * 4);
    float* shift    = (float*)alloc(64 * 4);
    (void)ws_size; (void)n_in; (void)out_size;

    hipMemsetAsync(d_ws, 0, zero_bytes, stream);

    // 1. pack B
    pack_b_kernel<<<(IN_F * TOTC + 255) / 256, 256, 0, stream>>>(W_fc, gat_res_w, res_w, Bc);
    // 2. GEMM
    dim3 ggrid((N + 63) / 64, TOTC / 64);
    gemm_kernel<<<ggrid, 256, 0, stream>>>(node_feats, Bc, HW, N);
    // 3. el/er
    elr_kernel<<<(N + 3) / 4, 256, 0, stream>>>(HW, attn_l, attn_r, el, er, N);
    // 4. edge scores
    edge_score_kernel<<<(E + 255) / 256, 256, 0, stream>>>(src, dst, el, er, s, ssum, degree, E);
    // 5. scan
    scan_kernel<<<1, 1024, 0, stream>>>(degree, offsets, cursor, N);
    // 6. scatter
    scatter_kernel<<<(E + 255) / 256, 256, 0, stream>>>(dst, cursor, edge_ids, E);
    // 7. aggregation + epilogue
    agg_kernel<<<N, 64, 0, stream>>>(HW, s, ssum, offsets, edge_ids, src,
                                     gat_bias, conv_w, conv_b, res_b, y, N);
    // 8. BN partial
    bn_partial_kernel<<<128, 256, 0, stream>>>(y, bnsum, bnsumsq, N * OUTD);
    // 9. BN finalize
    bn_final_kernel<<<1, 64, 0, stream>>>(bnsum, bnsumsq, bn_gamma, bn_beta, scale, shift, N);
    // 10. normalize -> out
    norm_kernel<<<(N * OUTD / 4 + 255) / 256, 256, 0, stream>>>(y, scale, shift, (float*)d_out,
                                                                N * OUTD / 4);
}

// Round 2
// 420.014 us; speedup vs baseline: 1.8267x; 1.8267x over previous
//
#include <hip/hip_runtime.h>

#define IN_F   128
#define OUTD   64
#define HOUT   256      // H*OUT
#define RESTC  320      // gat_res (256) + outer res (64)
#define NEG_SLOPE 0.2f
#define BN_EPS 1e-5f
#define HIST_BLOCKS 512

// ============ K1: fused  [histogram+rank]  +  GEMM [N x 128]@[128 x 576] + el/er ============
// blocks [0, HIST_BLOCKS): per-edge rank = atomicAdd(degree[dst]) (hidden under GEMM)
// blocks [HIST_BLOCKS, ...): 64x64 GEMM tiles; n-tiles 0..3 -> Hh (h), 4..8 -> Hrest;
//                            h-tiles also compute el/er via in-block shuffle reduce.
__global__ __launch_bounds__(256) void k1_gemm_hist(
    const float* __restrict__ A,
    const float* __restrict__ W_fc, const float* __restrict__ W_gres,
    const float* __restrict__ W_res,
    const float* __restrict__ attn_l, const float* __restrict__ attn_r,
    const int* __restrict__ dst,
    int* __restrict__ degree, int* __restrict__ rank,
    float* __restrict__ Hh, float* __restrict__ Hrest,
    float* __restrict__ el, float* __restrict__ er,
    int N, int E, int Mtiles)
{
    __shared__ float As[64][132];
    __shared__ float Bs[128][64];
    int bid = blockIdx.x;
    int t = threadIdx.x;

    if (bid < HIST_BLOCKS) {
        for (int e = bid * 256 + t; e < E; e += HIST_BLOCKS * 256)
            rank[e] = atomicAdd(degree + dst[e], 1);
        return;
    }

    int g = bid - HIST_BLOCKS;
    int m0 = (g % Mtiles) * 64;
    int n0 = (g / Mtiles) * 64;

    // B source select (uniform per block: 64-col tile never straddles a region)
    const float* Bsrc; int bstride, bcol;
    if (n0 < HOUT)            { Bsrc = W_fc;   bstride = HOUT; bcol = n0; }
    else if (n0 < 2 * HOUT)   { Bsrc = W_gres; bstride = HOUT; bcol = n0 - HOUT; }
    else                      { Bsrc = W_res;  bstride = OUTD; bcol = 0; }

    // stage A (64x128) and B (128x64)
    for (int i = 0; i < 8; ++i) {
        int slot = t + i * 256;
        int r = slot >> 5, c4 = (slot & 31) << 2;
        float4 v = make_float4(0.f, 0.f, 0.f, 0.f);
        if (m0 + r < N) v = *(const float4*)(A + (size_t)(m0 + r) * IN_F + c4);
        *(float4*)(&As[r][c4]) = v;
    }
    for (int i = 0; i < 8; ++i) {
        int slot = t + i * 256;
        int r = slot >> 4, c4 = (slot & 15) << 2;
        *(float4*)(&Bs[r][c4]) = *(const float4*)(Bsrc + (size_t)r * bstride + bcol + c4);
    }
    __syncthreads();

    int tm = t >> 4, tn = t & 15;
    float acc[4][4] = {};
    for (int k = 0; k < IN_F; k += 4) {
        float4 a[4], b[4];
#pragma unroll
        for (int i = 0; i < 4; ++i) a[i] = *(const float4*)(&As[tm * 4 + i][k]);
#pragma unroll
        for (int kk = 0; kk < 4; ++kk) b[kk] = *(const float4*)(&Bs[k + kk][tn * 4]);
#pragma unroll
        for (int i = 0; i < 4; ++i) {
            float ax = a[i].x, ay = a[i].y, az = a[i].z, aw = a[i].w;
            acc[i][0] += ax * b[0].x + ay * b[1].x + az * b[2].x + aw * b[3].x;
            acc[i][1] += ax * b[0].y + ay * b[1].y + az * b[2].y + aw * b[3].y;
            acc[i][2] += ax * b[0].z + ay * b[1].z + az * b[2].z + aw * b[3].z;
            acc[i][3] += ax * b[0].w + ay * b[1].w + az * b[2].w + aw * b[3].w;
        }
    }

    // store
    float* Outp; int ostride, ocol;
    if (n0 < HOUT) { Outp = Hh;    ostride = HOUT;  ocol = n0; }
    else           { Outp = Hrest; ostride = RESTC; ocol = n0 - HOUT; }
#pragma unroll
    for (int i = 0; i < 4; ++i) {
        int r = m0 + tm * 4 + i;
        if (r < N)
            *(float4*)(Outp + (size_t)r * ostride + ocol + tn * 4) =
                make_float4(acc[i][0], acc[i][1], acc[i][2], acc[i][3]);
    }

    // el/er for h tiles (one head per n-tile)
    if (n0 < HOUT) {
        int head = n0 >> 6;
        float4 alv = *(const float4*)(attn_l + n0 + tn * 4);
        float4 arv = *(const float4*)(attn_r + n0 + tn * 4);
#pragma unroll
        for (int i = 0; i < 4; ++i) {
            float pl = acc[i][0] * alv.x + acc[i][1] * alv.y + acc[i][2] * alv.z + acc[i][3] * alv.w;
            float pr = acc[i][0] * arv.x + acc[i][1] * arv.y + acc[i][2] * arv.z + acc[i][3] * arv.w;
#pragma unroll
            for (int off = 1; off < 16; off <<= 1) {
                pl += __shfl_xor(pl, off);
                pr += __shfl_xor(pr, off);
            }
            if (tn == 0) {
                int r = m0 + tm * 4 + i;
                if (r < N) { el[(size_t)r * 4 + head] = pl; er[(size_t)r * 4 + head] = pr; }
            }
        }
    }
}

// ============ hierarchical scan: per-256 chunk exclusive scans + block bases ============
__global__ __launch_bounds__(256) void scanA_kernel(const int* __restrict__ degree,
                                                    int* __restrict__ excl,
                                                    int* __restrict__ blocksum, int N) {
    __shared__ int sm[256];
    int t = threadIdx.x;
    int i = blockIdx.x * 256 + t;
    int d = (i < N) ? degree[i] : 0;
    sm[t] = d; __syncthreads();
    for (int off = 1; off < 256; off <<= 1) {
        int v = (t >= off) ? sm[t - off] : 0;
        __syncthreads();
        sm[t] += v;
        __syncthreads();
    }
    if (i < N) excl[i] = sm[t] - d;
    if (t == 255) blocksum[blockIdx.x] = sm[255];
}

__global__ __launch_bounds__(256) void scanB_kernel(const int* __restrict__ blocksum,
                                                    int* __restrict__ base, int nb) {
    __shared__ int sm[256];
    int t = threadIdx.x;
    int d = (t < nb) ? blocksum[t] : 0;
    sm[t] = d; __syncthreads();
    for (int off = 1; off < 256; off <<= 1) {
        int v = (t >= off) ? sm[t - off] : 0;
        __syncthreads();
        sm[t] += v;
        __syncthreads();
    }
    if (t < nb) base[t] = sm[t] - d;
}

// ============ atomic-free scatter using precomputed rank ============
__global__ void scatter_kernel(const int* __restrict__ src, const int* __restrict__ dst,
                               const int* __restrict__ rank, const int* __restrict__ excl,
                               const int* __restrict__ base, int* __restrict__ src_sorted, int E) {
    int e = blockIdx.x * 256 + threadIdx.x;
    if (e >= E) return;
    int d = dst[e];
    int p = excl[d] + base[d >> 8] + rank[e];
    src_sorted[p] = src[e];
}

// ============ aggregation: one wave per dst node, scores in registers, shfl broadcast ============
__global__ __launch_bounds__(256) void agg_kernel(
    const float* __restrict__ Hh, const float* __restrict__ Hrest,
    const float* __restrict__ el, const float* __restrict__ er,
    const int* __restrict__ excl, const int* __restrict__ base,
    const int* __restrict__ src_sorted,
    const float* __restrict__ gat_bias, const float* __restrict__ conv_w,
    const float* __restrict__ conv_b, const float* __restrict__ res_b,
    float* __restrict__ y, int N, int E)
{
    int wave = threadIdx.x >> 6, lane = threadIdx.x & 63;
    int v = blockIdx.x * 4 + wave;
    if (v >= N) return;
    int b  = excl[v] + base[v >> 8];
    int e2 = (v + 1 < N) ? (excl[v + 1] + base[(v + 1) >> 8]) : E;
    int deg = e2 - b;

    float4 rv = *(const float4*)(er + (size_t)v * 4);
    float a0 = 0.f, a1 = 0.f, a2 = 0.f, a3 = 0.f;   // sum s*h (this lane's column)
    float p0 = 0.f, p1 = 0.f, p2 = 0.f, p3 = 0.f;   // sum s (softmax denom partials)

    for (int i0 = 0; i0 < deg; i0 += 64) {
        int j = i0 + lane;
        int u = 0;
        float s0 = 0.f, s1 = 0.f, s2 = 0.f, s3 = 0.f;
        if (j < deg) {
            u = src_sorted[b + j];
            float4 l = *(const float4*)(el + (size_t)u * 4);
            float x;
            x = l.x + rv.x; x = x > 0.f ? x : NEG_SLOPE * x; s0 = __expf(x);
            x = l.y + rv.y; x = x > 0.f ? x : NEG_SLOPE * x; s1 = __expf(x);
            x = l.z + rv.z; x = x > 0.f ? x : NEG_SLOPE * x; s2 = __expf(x);
            x = l.w + rv.w; x = x > 0.f ? x : NEG_SLOPE * x; s3 = __expf(x);
        }
        p0 += s0; p1 += s1; p2 += s2; p3 += s3;
        int cl = deg - i0; if (cl > 64) cl = 64;
        for (int jj = 0; jj < cl; ++jj) {
            int uu = __shfl(u, jj);
            float w0 = __shfl(s0, jj), w1 = __shfl(s1, jj);
            float w2 = __shfl(s2, jj), w3 = __shfl(s3, jj);
            const float* hp = Hh + (size_t)uu * HOUT + lane;
            a0 += w0 * hp[0];
            a1 += w1 * hp[64];
            a2 += w2 * hp[128];
            a3 += w3 * hp[192];
        }
    }
#pragma unroll
    for (int off = 1; off < 64; off <<= 1) {
        p0 += __shfl_xor(p0, off); p1 += __shfl_xor(p1, off);
        p2 += __shfl_xor(p2, off); p3 += __shfl_xor(p3, off);
    }
    float r0 = 1.f / (p0 + 1e-16f), r1 = 1.f / (p1 + 1e-16f);
    float r2 = 1.f / (p2 + 1e-16f), r3 = 1.f / (p3 + 1e-16f);

    const float* hr = Hrest + (size_t)v * RESTC;
    float yv = conv_b[0];
    float tt;
    tt = a0 * r0 + hr[lane]       + gat_bias[lane];       tt = tt > 0.f ? tt : 0.f; yv += conv_w[0] * tt;
    tt = a1 * r1 + hr[64 + lane]  + gat_bias[64 + lane];  tt = tt > 0.f ? tt : 0.f; yv += conv_w[1] * tt;
    tt = a2 * r2 + hr[128 + lane] + gat_bias[128 + lane]; tt = tt > 0.f ? tt : 0.f; yv += conv_w[2] * tt;
    tt = a3 * r3 + hr[192 + lane] + gat_bias[192 + lane]; tt = tt > 0.f ? tt : 0.f; yv += conv_w[3] * tt;
    float resv = hr[256 + lane] + res_b[lane];
    yv += resv > 0.f ? resv : 0.f;
    y[(size_t)v * OUTD + lane] = yv;
}

// ============ BN tail ============
__global__ __launch_bounds__(256) void bn_partial_kernel(const float* __restrict__ y,
                                                         float* __restrict__ bnsum,
                                                         float* __restrict__ bnsumsq, int total) {
    __shared__ float smem[256];
    int t = threadIdx.x;
    size_t idx = (size_t)blockIdx.x * 256 + t;
    size_t stride = (size_t)gridDim.x * 256;   // multiple of 64 -> column fixed per thread
    float sum = 0.f, sq = 0.f;
    for (; idx < (size_t)total; idx += stride) {
        float v = y[idx];
        sum += v; sq += v * v;
    }
    int d = t & 63;
    smem[t] = sum; __syncthreads();
    if (t < 64) atomicAdd(bnsum + d, smem[t] + smem[t + 64] + smem[t + 128] + smem[t + 192]);
    __syncthreads();
    smem[t] = sq; __syncthreads();
    if (t < 64) atomicAdd(bnsumsq + d, smem[t] + smem[t + 64] + smem[t + 128] + smem[t + 192]);
}

__global__ void bn_final_kernel(const float* __restrict__ bnsum, const float* __restrict__ bnsumsq,
                                const float* __restrict__ gamma, const float* __restrict__ beta,
                                float* __restrict__ scale, float* __restrict__ shift, int N) {
    int d = threadIdx.x;
    if (d >= 64) return;
    float invN = 1.f / (float)N;
    float mean = bnsum[d] * invN;
    float var = bnsumsq[d] * invN - mean * mean;
    float sc = gamma[d] * rsqrtf(var + BN_EPS);
    scale[d] = sc;
    shift[d] = beta[d] - mean * sc;
}

__global__ void norm_kernel(const float* __restrict__ y, const float* __restrict__ scale,
                            const float* __restrict__ shift, float* __restrict__ out, int total4) {
    int idx = blockIdx.x * blockDim.x + threadIdx.x;
    if (idx >= total4) return;
    float4 v = *(const float4*)(y + (size_t)idx * 4);
    int d = (idx * 4) & 63;
    float4 o;
    o.x = v.x * scale[d + 0] + shift[d + 0];
    o.y = v.y * scale[d + 1] + shift[d + 1];
    o.z = v.z * scale[d + 2] + shift[d + 2];
    o.w = v.w * scale[d + 3] + shift[d + 3];
    *(float4*)(out + (size_t)idx * 4) = o;
}

// ============ launch ============
extern "C" void kernel_launch(void* const* d_in, const int* in_sizes, int n_in,
                              void* d_out, int out_size, void* d_ws, size_t ws_size,
                              hipStream_t stream) {
    const float* node_feats = (const float*)d_in[0];
    const float* W_fc       = (const float*)d_in[1];
    const float* attn_l     = (const float*)d_in[2];
    const float* attn_r     = (const float*)d_in[3];
    const float* gat_res_w  = (const float*)d_in[4];
    const float* gat_bias   = (const float*)d_in[5];
    const float* conv_w     = (const float*)d_in[6];
    const float* conv_b     = (const float*)d_in[7];
    const float* res_w      = (const float*)d_in[8];
    const float* res_b      = (const float*)d_in[9];
    const float* bn_gamma   = (const float*)d_in[10];
    const float* bn_beta    = (const float*)d_in[11];
    const int*   src        = (const int*)d_in[12];
    const int*   dst        = (const int*)d_in[13];

    const int N = in_sizes[0] / IN_F;
    const int E = in_sizes[12];
    const int Mtiles = (N + 63) / 64;
    const int nb = (N + 255) / 256;   // scan chunks of 256

    char* ws = (char*)d_ws;
    size_t off = 0;
    auto alloc = [&](size_t bytes) -> void* {
        void* p = (void*)(ws + off);
        off += (bytes + 255) & ~(size_t)255;
        return p;
    };

    // --- zero zone ---
    int*   degree  = (int*)alloc((size_t)N * 4);
    float* bnsum   = (float*)alloc(64 * 4);
    float* bnsumsq = (float*)alloc(64 * 4);
    size_t zero_bytes = off;
    // --- rest ---
    int*   rank       = (int*)alloc((size_t)E * 4);
    int*   excl       = (int*)alloc((size_t)N * 4);
    int*   blocksum   = (int*)alloc(256 * 4);
    int*   base       = (int*)alloc(256 * 4);
    int*   src_sorted = (int*)alloc((size_t)E * 4);
    float* Hh         = (float*)alloc((size_t)N * HOUT * 4);
    float* Hrest      = (float*)alloc((size_t)N * RESTC * 4);
    float* el         = (float*)alloc((size_t)N * 4 * 4);
    float* er         = (float*)alloc((size_t)N * 4 * 4);
    float* y          = (float*)alloc((size_t)N * OUTD * 4);
    float* scale      = (float*)alloc(64 * 4);
    float* shift      = (float*)alloc(64 * 4);
    (void)ws_size; (void)n_in; (void)out_size;

    hipMemsetAsync(d_ws, 0, zero_bytes, stream);

    // 1. fused GEMM + histogram(rank) + el/er
    int k1_blocks = HIST_BLOCKS + Mtiles * 9;
    k1_gemm_hist<<<k1_blocks, 256, 0, stream>>>(node_feats, W_fc, gat_res_w, res_w,
                                                attn_l, attn_r, dst, degree, rank,
                                                Hh, Hrest, el, er, N, E, Mtiles);
    // 2. hierarchical scan
    scanA_kernel<<<nb, 256, 0, stream>>>(degree, excl, blocksum, N);
    scanB_kernel<<<1, 256, 0, stream>>>(blocksum, base, nb);
    // 3. atomic-free scatter
    scatter_kernel<<<(E + 255) / 256, 256, 0, stream>>>(src, dst, rank, excl, base, src_sorted, E);
    // 4. aggregation + epilogue
    agg_kernel<<<(N + 3) / 4, 256, 0, stream>>>(Hh, Hrest, el, er, excl, base, src_sorted,
                                                gat_bias, conv_w, conv_b, res_b, y, N, E);
    // 5. BN
    bn_partial_kernel<<<512, 256, 0, stream>>>(y, bnsum, bnsumsq, N * OUTD);
    bn_final_kernel<<<1, 64, 0, stream>>>(bnsum, bnsumsq, bn_gamma, bn_beta, scale, shift, N);
    norm_kernel<<<(N * OUTD / 4 + 255) / 256, 256, 0, stream>>>(y, scale, shift, (float*)d_out,
                                                                N * OUTD / 4);
}

// Round 3
// 305.571 us; speedup vs baseline: 2.5109x; 1.3745x over previous
//
#include <hip/hip_runtime.h>

#define IN_F   128
#define OUTD   64
#define HOUT   256      // H*OUT
#define RESTC  320      // gat_res (256) + outer res (64)
#define NEG_SLOPE 0.2f
#define BN_EPS 1e-5f
#define HIST_BLOCKS 512
#define BPAD 136        // 128 + 8 shorts pad: quad-lane rows land 2-way on banks (free)

typedef __attribute__((ext_vector_type(8))) short bf16x8;
typedef __attribute__((ext_vector_type(4))) float f32x4;

__device__ __forceinline__ unsigned short f2bf(float f) {
    union { float f; unsigned u; } v; v.f = f;
    unsigned r = (v.u + 0x7FFF + ((v.u >> 16) & 1)) >> 16;   // RNE
    return (unsigned short)r;
}
__device__ __forceinline__ float bf2f(unsigned short h) {
    union { unsigned u; float f; } v; v.u = ((unsigned)h) << 16;
    return v.f;
}

// ============ K0: convert A -> bf16; pack W_fc|W_gres|W_res -> Btg[576][128] bf16 (k-contig) ============
__global__ __launch_bounds__(256) void k0_convert(
    const float* __restrict__ A,
    const float* __restrict__ W_fc, const float* __restrict__ W_gres,
    const float* __restrict__ W_res,
    unsigned short* __restrict__ Abf, unsigned short* __restrict__ Btg, int N)
{
    int bid = blockIdx.x, t = threadIdx.x;
    if (bid < 288) {                       // 576*128 / 256 = 288 blocks for B
        int idx = bid * 256 + t;           // idx = c*128 + k
        int c = idx >> 7, k = idx & 127;
        float v;
        if (c < 256)      v = W_fc[k * HOUT + c];
        else if (c < 512) v = W_gres[k * HOUT + (c - 256)];
        else              v = W_res[k * OUTD + (c - 512)];
        Btg[idx] = f2bf(v);
        return;
    }
    int i4 = (bid - 288) * 256 + t;        // float4 index
    if (i4 < N * (IN_F / 4)) {
        float4 v = *(const float4*)(A + (size_t)i4 * 4);
        ushort4 o;
        o.x = f2bf(v.x); o.y = f2bf(v.y); o.z = f2bf(v.z); o.w = f2bf(v.w);
        *(ushort4*)(Abf + (size_t)i4 * 4) = o;
    }
}

// ============ K1: MFMA GEMM [N x 128]@[128 x 576] -> bf16 Hh/Hrest, + fused histogram ============
__global__ __launch_bounds__(256) void k1_gemm(
    const unsigned short* __restrict__ Abf, const unsigned short* __restrict__ Btg,
    const int* __restrict__ dst, int* __restrict__ degree, int* __restrict__ rank,
    unsigned short* __restrict__ Hh, unsigned short* __restrict__ Hrest,
    int N, int E, int Mtiles)
{
    __shared__ __align__(16) unsigned short As[128 * BPAD];
    __shared__ __align__(16) unsigned short Bs[64 * BPAD];
    int bid = blockIdx.x, t = threadIdx.x;

    if (bid < HIST_BLOCKS) {   // histogram+rank, hidden under GEMM blocks
        for (int e = bid * 256 + t; e < E; e += HIST_BLOCKS * 256)
            rank[e] = atomicAdd(degree + dst[e], 1);
        return;
    }

    int g = bid - HIST_BLOCKS;
    int m0 = (g % Mtiles) * 128;
    int n0 = (g / Mtiles) * 64;

    // stage A tile: 128 rows x 128 k (bf16), 8 rounds of uint4
    for (int i = 0; i < 8; ++i) {
        int slot = t + i * 256;
        int r = slot >> 4, k0 = (slot & 15) << 3;
        uint4 v = make_uint4(0u, 0u, 0u, 0u);
        int rg = m0 + r;
        if (rg < N) v = *(const uint4*)(Abf + (size_t)rg * IN_F + k0);
        *(uint4*)(&As[r * BPAD + k0]) = v;
    }
    // stage B tile: 64 cols x 128 k (bf16, k-contig), 4 rounds
    for (int i = 0; i < 4; ++i) {
        int slot = t + i * 256;
        int c = slot >> 4, k0 = (slot & 15) << 3;
        *(uint4*)(&Bs[c * BPAD + k0]) = *(const uint4*)(Btg + (size_t)(n0 + c) * IN_F + k0);
    }
    __syncthreads();

    int w = t >> 6, lane = t & 63, quad = lane >> 4, n15 = lane & 15;
    f32x4 acc[2][4] = {};
#pragma unroll
    for (int ks = 0; ks < 4; ++ks) {
        bf16x8 af[2], bfr[4];
#pragma unroll
        for (int i = 0; i < 2; ++i)
            af[i] = *(const bf16x8*)(&As[(w * 32 + i * 16 + n15) * BPAD + ks * 32 + quad * 8]);
#pragma unroll
        for (int j = 0; j < 4; ++j)
            bfr[j] = *(const bf16x8*)(&Bs[(j * 16 + n15) * BPAD + ks * 32 + quad * 8]);
#pragma unroll
        for (int i = 0; i < 2; ++i)
#pragma unroll
            for (int j = 0; j < 4; ++j)
                acc[i][j] = __builtin_amdgcn_mfma_f32_16x16x32_bf16(af[i], bfr[j], acc[i][j], 0, 0, 0);
    }

    unsigned short* outp; int ostride, c0;
    if (n0 < HOUT) { outp = Hh;    ostride = HOUT;  c0 = n0; }
    else           { outp = Hrest; ostride = RESTC; c0 = n0 - HOUT; }
#pragma unroll
    for (int i = 0; i < 2; ++i) {
        int rbase = m0 + w * 32 + i * 16 + quad * 4;
#pragma unroll
        for (int reg = 0; reg < 4; ++reg) {
            int r = rbase + reg;
            if (r < N) {
#pragma unroll
                for (int j = 0; j < 4; ++j)
                    outp[(size_t)r * ostride + c0 + j * 16 + n15] = f2bf(acc[i][j][reg]);
            }
        }
    }
}

// ============ el/er from bf16 Hh: one wave per node ============
__global__ __launch_bounds__(256) void elr_kernel(const unsigned short* __restrict__ Hh,
                                                  const float* __restrict__ attn_l,
                                                  const float* __restrict__ attn_r,
                                                  float* __restrict__ el,
                                                  float* __restrict__ er, int N) {
    int wave = threadIdx.x >> 6, lane = threadIdx.x & 63;
    int v = blockIdx.x * 4 + wave;
    if (v >= N) return;
    float pl[4], pr[4];
#pragma unroll
    for (int hd = 0; hd < 4; ++hd) {
        float hv = bf2f(Hh[(size_t)v * HOUT + hd * 64 + lane]);
        pl[hd] = hv * attn_l[hd * 64 + lane];
        pr[hd] = hv * attn_r[hd * 64 + lane];
    }
#pragma unroll
    for (int off = 32; off; off >>= 1) {
#pragma unroll
        for (int hd = 0; hd < 4; ++hd) {
            pl[hd] += __shfl_down(pl[hd], off);
            pr[hd] += __shfl_down(pr[hd], off);
        }
    }
    if (lane == 0) {
        *(float4*)(el + (size_t)v * 4) = make_float4(pl[0], pl[1], pl[2], pl[3]);
        *(float4*)(er + (size_t)v * 4) = make_float4(pr[0], pr[1], pr[2], pr[3]);
    }
}

// ============ hierarchical scan ============
__global__ __launch_bounds__(256) void scanA_kernel(const int* __restrict__ degree,
                                                    int* __restrict__ excl,
                                                    int* __restrict__ blocksum, int N) {
    __shared__ int sm[256];
    int t = threadIdx.x;
    int i = blockIdx.x * 256 + t;
    int d = (i < N) ? degree[i] : 0;
    sm[t] = d; __syncthreads();
    for (int off = 1; off < 256; off <<= 1) {
        int v = (t >= off) ? sm[t - off] : 0;
        __syncthreads();
        sm[t] += v;
        __syncthreads();
    }
    if (i < N) excl[i] = sm[t] - d;
    if (t == 255) blocksum[blockIdx.x] = sm[255];
}

__global__ __launch_bounds__(256) void scanB_kernel(const int* __restrict__ blocksum,
                                                    int* __restrict__ base, int nb) {
    __shared__ int sm[256];
    int t = threadIdx.x;
    int d = (t < nb) ? blocksum[t] : 0;
    sm[t] = d; __syncthreads();
    for (int off = 1; off < 256; off <<= 1) {
        int v = (t >= off) ? sm[t - off] : 0;
        __syncthreads();
        sm[t] += v;
        __syncthreads();
    }
    if (t < nb) base[t] = sm[t] - d;
}

// ============ atomic-free scatter ============
__global__ void scatter_kernel(const int* __restrict__ src, const int* __restrict__ dst,
                               const int* __restrict__ rank, const int* __restrict__ excl,
                               const int* __restrict__ base, int* __restrict__ src_sorted, int E) {
    int e = blockIdx.x * 256 + threadIdx.x;
    if (e >= E) return;
    int d = dst[e];
    int p = excl[d] + base[d >> 8] + rank[e];
    src_sorted[p] = src[e];
}

// ============ aggregation + epilogue (bf16 Hh/Hrest) ============
__global__ __launch_bounds__(256) void agg_kernel(
    const unsigned short* __restrict__ Hh, const unsigned short* __restrict__ Hrest,
    const float* __restrict__ el, const float* __restrict__ er,
    const int* __restrict__ excl, const int* __restrict__ base,
    const int* __restrict__ src_sorted,
    const float* __restrict__ gat_bias, const float* __restrict__ conv_w,
    const float* __restrict__ conv_b, const float* __restrict__ res_b,
    float* __restrict__ y, int N, int E)
{
    int wave = threadIdx.x >> 6, lane = threadIdx.x & 63;
    int v = blockIdx.x * 4 + wave;
    if (v >= N) return;
    int b  = excl[v] + base[v >> 8];
    int e2 = (v + 1 < N) ? (excl[v + 1] + base[(v + 1) >> 8]) : E;
    int deg = e2 - b;

    float4 rv = *(const float4*)(er + (size_t)v * 4);
    float a0 = 0.f, a1 = 0.f, a2 = 0.f, a3 = 0.f;
    float p0 = 0.f, p1 = 0.f, p2 = 0.f, p3 = 0.f;

    for (int i0 = 0; i0 < deg; i0 += 64) {
        int j = i0 + lane;
        int u = 0;
        float s0 = 0.f, s1 = 0.f, s2 = 0.f, s3 = 0.f;
        if (j < deg) {
            u = src_sorted[b + j];
            float4 l = *(const float4*)(el + (size_t)u * 4);
            float x;
            x = l.x + rv.x; x = x > 0.f ? x : NEG_SLOPE * x; s0 = __expf(x);
            x = l.y + rv.y; x = x > 0.f ? x : NEG_SLOPE * x; s1 = __expf(x);
            x = l.z + rv.z; x = x > 0.f ? x : NEG_SLOPE * x; s2 = __expf(x);
            x = l.w + rv.w; x = x > 0.f ? x : NEG_SLOPE * x; s3 = __expf(x);
        }
        p0 += s0; p1 += s1; p2 += s2; p3 += s3;
        int cl = deg - i0; if (cl > 64) cl = 64;
        for (int jj = 0; jj < cl; ++jj) {
            int uu = __shfl(u, jj);
            float w0 = __shfl(s0, jj), w1 = __shfl(s1, jj);
            float w2 = __shfl(s2, jj), w3 = __shfl(s3, jj);
            const unsigned short* hp = Hh + (size_t)uu * HOUT + lane;
            a0 += w0 * bf2f(hp[0]);
            a1 += w1 * bf2f(hp[64]);
            a2 += w2 * bf2f(hp[128]);
            a3 += w3 * bf2f(hp[192]);
        }
    }
#pragma unroll
    for (int off = 1; off < 64; off <<= 1) {
        p0 += __shfl_xor(p0, off); p1 += __shfl_xor(p1, off);
        p2 += __shfl_xor(p2, off); p3 += __shfl_xor(p3, off);
    }
    float r0 = 1.f / (p0 + 1e-16f), r1 = 1.f / (p1 + 1e-16f);
    float r2 = 1.f / (p2 + 1e-16f), r3 = 1.f / (p3 + 1e-16f);

    const unsigned short* hr = Hrest + (size_t)v * RESTC;
    float yv = conv_b[0];
    float tt;
    tt = a0 * r0 + bf2f(hr[lane])       + gat_bias[lane];       tt = tt > 0.f ? tt : 0.f; yv += conv_w[0] * tt;
    tt = a1 * r1 + bf2f(hr[64 + lane])  + gat_bias[64 + lane];  tt = tt > 0.f ? tt : 0.f; yv += conv_w[1] * tt;
    tt = a2 * r2 + bf2f(hr[128 + lane]) + gat_bias[128 + lane]; tt = tt > 0.f ? tt : 0.f; yv += conv_w[2] * tt;
    tt = a3 * r3 + bf2f(hr[192 + lane]) + gat_bias[192 + lane]; tt = tt > 0.f ? tt : 0.f; yv += conv_w[3] * tt;
    float resv = bf2f(hr[256 + lane]) + res_b[lane];
    yv += resv > 0.f ? resv : 0.f;
    y[(size_t)v * OUTD + lane] = yv;
}

// ============ BN tail ============
__global__ __launch_bounds__(256) void bn_partial_kernel(const float* __restrict__ y,
                                                         float* __restrict__ bnsum,
                                                         float* __restrict__ bnsumsq, int total) {
    __shared__ float smem[256];
    int t = threadIdx.x;
    size_t idx = (size_t)blockIdx.x * 256 + t;
    size_t stride = (size_t)gridDim.x * 256;
    float sum = 0.f, sq = 0.f;
    for (; idx < (size_t)total; idx += stride) {
        float v = y[idx];
        sum += v; sq += v * v;
    }
    int d = t & 63;
    smem[t] = sum; __syncthreads();
    if (t < 64) atomicAdd(bnsum + d, smem[t] + smem[t + 64] + smem[t + 128] + smem[t + 192]);
    __syncthreads();
    smem[t] = sq; __syncthreads();
    if (t < 64) atomicAdd(bnsumsq + d, smem[t] + smem[t + 64] + smem[t + 128] + smem[t + 192]);
}

__global__ void bn_final_kernel(const float* __restrict__ bnsum, const float* __restrict__ bnsumsq,
                                const float* __restrict__ gamma, const float* __restrict__ beta,
                                float* __restrict__ scale, float* __restrict__ shift, int N) {
    int d = threadIdx.x;
    if (d >= 64) return;
    float invN = 1.f / (float)N;
    float mean = bnsum[d] * invN;
    float var = bnsumsq[d] * invN - mean * mean;
    float sc = gamma[d] * rsqrtf(var + BN_EPS);
    scale[d] = sc;
    shift[d] = beta[d] - mean * sc;
}

__global__ void norm_kernel(const float* __restrict__ y, const float* __restrict__ scale,
                            const float* __restrict__ shift, float* __restrict__ out, int total4) {
    int idx = blockIdx.x * blockDim.x + threadIdx.x;
    if (idx >= total4) return;
    float4 v = *(const float4*)(y + (size_t)idx * 4);
    int d = (idx * 4) & 63;
    float4 o;
    o.x = v.x * scale[d + 0] + shift[d + 0];
    o.y = v.y * scale[d + 1] + shift[d + 1];
    o.z = v.z * scale[d + 2] + shift[d + 2];
    o.w = v.w * scale[d + 3] + shift[d + 3];
    *(float4*)(out + (size_t)idx * 4) = o;
}

// ============ launch ============
extern "C" void kernel_launch(void* const* d_in, const int* in_sizes, int n_in,
                              void* d_out, int out_size, void* d_ws, size_t ws_size,
                              hipStream_t stream) {
    const float* node_feats = (const float*)d_in[0];
    const float* W_fc       = (const float*)d_in[1];
    const float* attn_l     = (const float*)d_in[2];
    const float* attn_r     = (const float*)d_in[3];
    const float* gat_res_w  = (const float*)d_in[4];
    const float* gat_bias   = (const float*)d_in[5];
    const float* conv_w     = (const float*)d_in[6];
    const float* conv_b     = (const float*)d_in[7];
    const float* res_w      = (const float*)d_in[8];
    const float* res_b      = (const float*)d_in[9];
    const float* bn_gamma   = (const float*)d_in[10];
    const float* bn_beta    = (const float*)d_in[11];
    const int*   src        = (const int*)d_in[12];
    const int*   dst        = (const int*)d_in[13];

    const int N = in_sizes[0] / IN_F;
    const int E = in_sizes[12];
    const int Mtiles = (N + 127) / 128;
    const int nb = (N + 255) / 256;

    char* ws = (char*)d_ws;
    size_t off = 0;
    auto alloc = [&](size_t bytes) -> void* {
        void* p = (void*)(ws + off);
        off += (bytes + 255) & ~(size_t)255;
        return p;
    };

    // --- zero zone ---
    int*   degree  = (int*)alloc((size_t)N * 4);
    float* bnsum   = (float*)alloc(64 * 4);
    float* bnsumsq = (float*)alloc(64 * 4);
    size_t zero_bytes = off;
    // --- rest ---
    int*            rank       = (int*)alloc((size_t)E * 4);
    int*            excl       = (int*)alloc((size_t)N * 4);
    int*            blocksum   = (int*)alloc(256 * 4);
    int*            base       = (int*)alloc(256 * 4);
    int*            src_sorted = (int*)alloc((size_t)E * 4);
    unsigned short* Abf        = (unsigned short*)alloc((size_t)N * IN_F * 2);
    unsigned short* Btg        = (unsigned short*)alloc((size_t)576 * IN_F * 2);
    unsigned short* Hh         = (unsigned short*)alloc((size_t)N * HOUT * 2);
    unsigned short* Hrest      = (unsigned short*)alloc((size_t)N * RESTC * 2);
    float*          el         = (float*)alloc((size_t)N * 4 * 4);
    float*          er         = (float*)alloc((size_t)N * 4 * 4);
    float*          y          = (float*)alloc((size_t)N * OUTD * 4);
    float*          scale      = (float*)alloc(64 * 4);
    float*          shift      = (float*)alloc(64 * 4);
    (void)ws_size; (void)n_in; (void)out_size;

    hipMemsetAsync(d_ws, 0, zero_bytes, stream);

    // 0. convert to bf16 + pack transposed B
    int a4blocks = (N * (IN_F / 4) + 255) / 256;
    k0_convert<<<288 + a4blocks, 256, 0, stream>>>(node_feats, W_fc, gat_res_w, res_w, Abf, Btg, N);
    // 1. MFMA GEMM + histogram
    k1_gemm<<<HIST_BLOCKS + Mtiles * 9, 256, 0, stream>>>(Abf, Btg, dst, degree, rank,
                                                          Hh, Hrest, N, E, Mtiles);
    // 2. el/er
    elr_kernel<<<(N + 3) / 4, 256, 0, stream>>>(Hh, attn_l, attn_r, el, er, N);
    // 3. scan
    scanA_kernel<<<nb, 256, 0, stream>>>(degree, excl, blocksum, N);
    scanB_kernel<<<1, 256, 0, stream>>>(blocksum, base, nb);
    // 4. scatter
    scatter_kernel<<<(E + 255) / 256, 256, 0, stream>>>(src, dst, rank, excl, base, src_sorted, E);
    // 5. aggregation + epilogue
    agg_kernel<<<(N + 3) / 4, 256, 0, stream>>>(Hh, Hrest, el, er, excl, base, src_sorted,
                                                gat_bias, conv_w, conv_b, res_b, y, N, E);
    // 6. BN
    bn_partial_kernel<<<512, 256, 0, stream>>>(y, bnsum, bnsumsq, N * OUTD);
    bn_final_kernel<<<1, 64, 0, stream>>>(bnsum, bnsumsq, bn_gamma, bn_beta, scale, shift, N);
    norm_kernel<<<(N * OUTD / 4 + 255) / 256, 256, 0, stream>>>(y, scale, shift, (float*)d_out,
                                                                N * OUTD / 4);
}

// Round 4
// 268.468 us; speedup vs baseline: 2.8579x; 1.1382x over previous
//
#include <hip/hip_runtime.h>

#define IN_F   128
#define OUTD   64
#define HOUT   256      // H*OUT
#define RESTC  320      // gat_res (256) + outer res (64)
#define NEG_SLOPE 0.2f
#define BN_EPS 1e-5f
#define HIST_BLOCKS 512
#define BPAD 136        // 128 + 8 shorts pad: row stride 272B -> 2-way bank alias (free)

typedef __attribute__((ext_vector_type(8))) short bf16x8;
typedef __attribute__((ext_vector_type(4))) float f32x4;
typedef __attribute__((ext_vector_type(2))) float f32x2;

__device__ __forceinline__ unsigned short f2bf(float f) {
    union { float f; unsigned u; } v; v.f = f;
    unsigned r = (v.u + 0x7FFF + ((v.u >> 16) & 1)) >> 16;   // RNE
    return (unsigned short)r;
}
__device__ __forceinline__ float bf2f(unsigned short h) {
    union { unsigned u; float f; } v; v.u = ((unsigned)h) << 16;
    return v.f;
}

// ============ K0: pack W_fc|W_gres|W_res -> Btg[576][128] bf16 (k-contig) ============
__global__ __launch_bounds__(256) void k0_pack(
    const float* __restrict__ W_fc, const float* __restrict__ W_gres,
    const float* __restrict__ W_res, unsigned short* __restrict__ Btg)
{
    int idx = blockIdx.x * 256 + threadIdx.x;   // idx = c*128 + k
    if (idx >= 576 * 128) return;
    int c = idx >> 7, k = idx & 127;
    float v;
    if (c < 256)      v = W_fc[k * HOUT + c];
    else if (c < 512) v = W_gres[k * HOUT + (c - 256)];
    else              v = W_res[k * OUTD + (c - 512)];
    Btg[idx] = f2bf(v);
}

// ============ K1: MFMA GEMM, m-tile loops all 9 n-tiles; fused histogram + el/er ============
// outputs: Hh8 fp8 e4m3 head-interleaved [r][col 0..63][head 0..3] (256 B/row)
//          Hrest bf16 row-major [r][c] c<256: gat_res, c>=256: outer res
//          el/er fp32 [r][4]
__global__ __launch_bounds__(256) void k1_gemm(
    const float* __restrict__ A, const unsigned short* __restrict__ Btg,
    const float* __restrict__ attn_l, const float* __restrict__ attn_r,
    const int* __restrict__ dst, int* __restrict__ degree, int* __restrict__ rank,
    unsigned char* __restrict__ Hh8, unsigned short* __restrict__ Hrest,
    float* __restrict__ el, float* __restrict__ er,
    int N, int E, int Mtiles)
{
    __shared__ __align__(16) unsigned short As[128 * BPAD];
    __shared__ __align__(16) unsigned short Bs[64 * BPAD];
    int bid = blockIdx.x, t = threadIdx.x;

    if (bid >= Mtiles) {   // histogram blocks (run concurrent with GEMM blocks)
        int hb = bid - Mtiles;
        for (int e = hb * 256 + t; e < E; e += HIST_BLOCKS * 256)
            rank[e] = atomicAdd(degree + dst[e], 1);
        return;
    }

    int m0 = bid * 128;

    // stage A tile: 128 rows x 128 k, fp32 -> bf16 in-register
    for (int i = 0; i < 16; ++i) {
        int slot = t + i * 256;            // 0..4095
        int r = slot >> 5, c4 = (slot & 31) << 2;
        float4 v = make_float4(0.f, 0.f, 0.f, 0.f);
        if (m0 + r < N) v = *(const float4*)(A + (size_t)(m0 + r) * IN_F + c4);
        ushort4 o;
        o.x = f2bf(v.x); o.y = f2bf(v.y); o.z = f2bf(v.z); o.w = f2bf(v.w);
        *(ushort4*)(&As[r * BPAD + c4]) = o;
    }

    int w = t >> 6, lane = t & 63, quad = lane >> 4, n15 = lane & 15;
    bf16x8 af[2][4];
    unsigned hpack[2][4][4] = {};   // [i][j][reg] fp8 bytes packed across heads

    for (int n = 0; n < 9; ++n) {
        if (n) __syncthreads();
        // stage B tile (64 cols x 128 k bf16)
        for (int i = 0; i < 4; ++i) {
            int slot = t + i * 256;
            int c = slot >> 4, k0 = (slot & 15) << 3;
            *(uint4*)(&Bs[c * BPAD + k0]) = *(const uint4*)(Btg + (size_t)(n * 64 + c) * IN_F + k0);
        }
        __syncthreads();
        if (n == 0) {
#pragma unroll
            for (int i = 0; i < 2; ++i)
#pragma unroll
                for (int ks = 0; ks < 4; ++ks)
                    af[i][ks] = *(const bf16x8*)(&As[(w * 32 + i * 16 + n15) * BPAD + ks * 32 + quad * 8]);
        }

        f32x4 acc[2][4] = {};
#pragma unroll
        for (int ks = 0; ks < 4; ++ks) {
            bf16x8 bfr[4];
#pragma unroll
            for (int j = 0; j < 4; ++j)
                bfr[j] = *(const bf16x8*)(&Bs[(j * 16 + n15) * BPAD + ks * 32 + quad * 8]);
#pragma unroll
            for (int i = 0; i < 2; ++i)
#pragma unroll
                for (int j = 0; j < 4; ++j)
                    acc[i][j] = __builtin_amdgcn_mfma_f32_16x16x32_bf16(af[i][ks], bfr[j], acc[i][j], 0, 0, 0);
        }

        if (n < 4) {
            // ---- el/er (fp32 accs) ----
            float alv[4], arv[4];
#pragma unroll
            for (int j = 0; j < 4; ++j) {
                alv[j] = attn_l[n * 64 + j * 16 + n15];
                arv[j] = attn_r[n * 64 + j * 16 + n15];
            }
#pragma unroll
            for (int i = 0; i < 2; ++i)
#pragma unroll
                for (int reg = 0; reg < 4; ++reg) {
                    float pl = acc[i][0][reg] * alv[0] + acc[i][1][reg] * alv[1]
                             + acc[i][2][reg] * alv[2] + acc[i][3][reg] * alv[3];
                    float pr = acc[i][0][reg] * arv[0] + acc[i][1][reg] * arv[1]
                             + acc[i][2][reg] * arv[2] + acc[i][3][reg] * arv[3];
#pragma unroll
                    for (int off = 1; off < 16; off <<= 1) {
                        pl += __shfl_xor(pl, off);
                        pr += __shfl_xor(pr, off);
                    }
                    int r = m0 + w * 32 + i * 16 + quad * 4 + reg;
                    if (n15 == 0 && r < N) {
                        el[(size_t)r * 4 + n] = pl;
                        er[(size_t)r * 4 + n] = pr;
                    }
                }
            // ---- pack fp8 byte (head n) ----
#pragma unroll
            for (int i = 0; i < 2; ++i)
#pragma unroll
                for (int j = 0; j < 4; ++j)
#pragma unroll
                    for (int reg = 0; reg < 4; ++reg) {
                        float v = acc[i][j][reg];
                        unsigned pk = (unsigned)__builtin_amdgcn_cvt_pk_fp8_f32(v, v, 0, false);
                        hpack[i][j][reg] |= (pk & 0xffu) << (8 * n);
                    }
        } else {
            // ---- Hrest bf16 stores (gat_res cols 0..255, res cols 256..319) ----
            int c0 = (n - 4) * 64;   // n==8 -> 256
#pragma unroll
            for (int i = 0; i < 2; ++i) {
                int rbase = m0 + w * 32 + i * 16 + quad * 4;
#pragma unroll
                for (int reg = 0; reg < 4; ++reg) {
                    int r = rbase + reg;
                    if (r < N) {
#pragma unroll
                        for (int j = 0; j < 4; ++j)
                            Hrest[(size_t)r * RESTC + c0 + j * 16 + n15] = f2bf(acc[i][j][reg]);
                    }
                }
            }
        }
    }

    // ---- store packed fp8 Hh ----
#pragma unroll
    for (int i = 0; i < 2; ++i) {
        int rbase = m0 + w * 32 + i * 16 + quad * 4;
#pragma unroll
        for (int reg = 0; reg < 4; ++reg) {
            int r = rbase + reg;
            if (r < N) {
#pragma unroll
                for (int j = 0; j < 4; ++j)
                    *(unsigned*)(Hh8 + (size_t)r * 256 + (j * 16 + n15) * 4) = hpack[i][j][reg];
            }
        }
    }
}

// ============ hierarchical scan ============
__global__ __launch_bounds__(256) void scanA_kernel(const int* __restrict__ degree,
                                                    int* __restrict__ excl,
                                                    int* __restrict__ blocksum, int N) {
    __shared__ int sm[256];
    int t = threadIdx.x;
    int i = blockIdx.x * 256 + t;
    int d = (i < N) ? degree[i] : 0;
    sm[t] = d; __syncthreads();
    for (int off = 1; off < 256; off <<= 1) {
        int v = (t >= off) ? sm[t - off] : 0;
        __syncthreads();
        sm[t] += v;
        __syncthreads();
    }
    if (i < N) excl[i] = sm[t] - d;
    if (t == 255) blocksum[blockIdx.x] = sm[255];
}

__global__ __launch_bounds__(256) void scanB_kernel(const int* __restrict__ blocksum,
                                                    int* __restrict__ base, int nb) {
    __shared__ int sm[256];
    int t = threadIdx.x;
    int d = (t < nb) ? blocksum[t] : 0;
    sm[t] = d; __syncthreads();
    for (int off = 1; off < 256; off <<= 1) {
        int v = (t >= off) ? sm[t - off] : 0;
        __syncthreads();
        sm[t] += v;
        __syncthreads();
    }
    if (t < nb) base[t] = sm[t] - d;
}

// ============ scatter + edge-score compute: es_sorted[p] = {src, s01, s23, 0} ============
__global__ void scatter_kernel(const int* __restrict__ src, const int* __restrict__ dst,
                               const int* __restrict__ rank, const int* __restrict__ excl,
                               const int* __restrict__ base,
                               const float* __restrict__ el, const float* __restrict__ er,
                               uint4* __restrict__ es_sorted, int E) {
    int e = blockIdx.x * 256 + threadIdx.x;
    if (e >= E) return;
    int d = dst[e], u = src[e];
    int p = excl[d] + base[d >> 8] + rank[e];
    float4 l = *(const float4*)(el + (size_t)u * 4);
    float4 r = *(const float4*)(er + (size_t)d * 4);
    float x, s0, s1, s2, s3;
    x = l.x + r.x; x = x > 0.f ? x : NEG_SLOPE * x; s0 = __expf(x);
    x = l.y + r.y; x = x > 0.f ? x : NEG_SLOPE * x; s1 = __expf(x);
    x = l.z + r.z; x = x > 0.f ? x : NEG_SLOPE * x; s2 = __expf(x);
    x = l.w + r.w; x = x > 0.f ? x : NEG_SLOPE * x; s3 = __expf(x);
    uint4 o;
    o.x = (unsigned)u;
    o.y = (unsigned)f2bf(s0) | ((unsigned)f2bf(s1) << 16);
    o.z = (unsigned)f2bf(s2) | ((unsigned)f2bf(s3) << 16);
    o.w = 0u;
    es_sorted[p] = o;
}

// ============ aggregation + epilogue: one wave per dst node, fp8 single-load gather ============
__global__ __launch_bounds__(256) void agg_kernel(
    const unsigned char* __restrict__ Hh8, const unsigned short* __restrict__ Hrest,
    const int* __restrict__ excl, const int* __restrict__ base,
    const uint4* __restrict__ es_sorted,
    const float* __restrict__ gat_bias, const float* __restrict__ conv_w,
    const float* __restrict__ conv_b, const float* __restrict__ res_b,
    float* __restrict__ y, int N, int E)
{
    int wave = threadIdx.x >> 6, lane = threadIdx.x & 63;
    int v = blockIdx.x * 4 + wave;
    if (v >= N) return;
    int b  = excl[v] + base[v >> 8];
    int e2 = (v + 1 < N) ? (excl[v + 1] + base[(v + 1) >> 8]) : E;
    int deg = e2 - b;

    float a0 = 0.f, a1 = 0.f, a2 = 0.f, a3 = 0.f;
    float p0 = 0.f, p1 = 0.f, p2 = 0.f, p3 = 0.f;

    for (int i0 = 0; i0 < deg; i0 += 64) {
        int j = i0 + lane;
        uint4 es = make_uint4(0u, 0u, 0u, 0u);
        if (j < deg) es = es_sorted[b + j];
        // denominator partials (invalid lanes contribute bf2f(0)=0)
        p0 += bf2f((unsigned short)(es.y & 0xffff));
        p1 += bf2f((unsigned short)(es.y >> 16));
        p2 += bf2f((unsigned short)(es.z & 0xffff));
        p3 += bf2f((unsigned short)(es.z >> 16));
        int cl = deg - i0; if (cl > 64) cl = 64;
        for (int jj = 0; jj < cl; ++jj) {
            unsigned uu  = __shfl(es.x, jj);
            unsigned s01 = __shfl(es.y, jj);
            unsigned s23 = __shfl(es.z, jj);
            unsigned hv = *(const unsigned*)(Hh8 + (size_t)uu * 256 + lane * 4);
            f32x2 lo = __builtin_amdgcn_cvt_pk_f32_fp8(hv, false);
            f32x2 hi = __builtin_amdgcn_cvt_pk_f32_fp8(hv, true);
            a0 += bf2f((unsigned short)(s01 & 0xffff)) * lo.x;
            a1 += bf2f((unsigned short)(s01 >> 16))    * lo.y;
            a2 += bf2f((unsigned short)(s23 & 0xffff)) * hi.x;
            a3 += bf2f((unsigned short)(s23 >> 16))    * hi.y;
        }
    }
#pragma unroll
    for (int off = 1; off < 64; off <<= 1) {
        p0 += __shfl_xor(p0, off); p1 += __shfl_xor(p1, off);
        p2 += __shfl_xor(p2, off); p3 += __shfl_xor(p3, off);
    }
    float r0 = 1.f / (p0 + 1e-16f), r1 = 1.f / (p1 + 1e-16f);
    float r2 = 1.f / (p2 + 1e-16f), r3 = 1.f / (p3 + 1e-16f);

    const unsigned short* hr = Hrest + (size_t)v * RESTC;
    float yv = conv_b[0];
    float tt;
    tt = a0 * r0 + bf2f(hr[lane])       + gat_bias[lane];       tt = tt > 0.f ? tt : 0.f; yv += conv_w[0] * tt;
    tt = a1 * r1 + bf2f(hr[64 + lane])  + gat_bias[64 + lane];  tt = tt > 0.f ? tt : 0.f; yv += conv_w[1] * tt;
    tt = a2 * r2 + bf2f(hr[128 + lane]) + gat_bias[128 + lane]; tt = tt > 0.f ? tt : 0.f; yv += conv_w[2] * tt;
    tt = a3 * r3 + bf2f(hr[192 + lane]) + gat_bias[192 + lane]; tt = tt > 0.f ? tt : 0.f; yv += conv_w[3] * tt;
    float resv = bf2f(hr[256 + lane]) + res_b[lane];
    yv += resv > 0.f ? resv : 0.f;
    y[(size_t)v * OUTD + lane] = yv;
}

// ============ BN tail ============
__global__ __launch_bounds__(256) void bn_partial_kernel(const float* __restrict__ y,
                                                         float* __restrict__ bnsum,
                                                         float* __restrict__ bnsumsq, int total) {
    __shared__ float smem[256];
    int t = threadIdx.x;
    size_t idx = (size_t)blockIdx.x * 256 + t;
    size_t stride = (size_t)gridDim.x * 256;
    float sum = 0.f, sq = 0.f;
    for (; idx < (size_t)total; idx += stride) {
        float v = y[idx];
        sum += v; sq += v * v;
    }
    int d = t & 63;
    smem[t] = sum; __syncthreads();
    if (t < 64) atomicAdd(bnsum + d, smem[t] + smem[t + 64] + smem[t + 128] + smem[t + 192]);
    __syncthreads();
    smem[t] = sq; __syncthreads();
    if (t < 64) atomicAdd(bnsumsq + d, smem[t] + smem[t + 64] + smem[t + 128] + smem[t + 192]);
}

// norm with fused bn-finalize (scale/shift recomputed per element from bnsum — L2-hot)
__global__ void norm_kernel(const float* __restrict__ y,
                            const float* __restrict__ bnsum, const float* __restrict__ bnsumsq,
                            const float* __restrict__ gamma, const float* __restrict__ beta,
                            float* __restrict__ out, int total4, float invN) {
    int idx = blockIdx.x * blockDim.x + threadIdx.x;
    if (idx >= total4) return;
    float4 v = *(const float4*)(y + (size_t)idx * 4);
    int d = (idx * 4) & 63;
    float4 o;
#pragma unroll
    for (int k = 0; k < 4; ++k) {
        float mean = bnsum[d + k] * invN;
        float var = bnsumsq[d + k] * invN - mean * mean;
        float sc = gamma[d + k] * rsqrtf(var + BN_EPS);
        float sh = beta[d + k] - mean * sc;
        float val = (&v.x)[k] * sc + sh;
        (&o.x)[k] = val;
    }
    *(float4*)(out + (size_t)idx * 4) = o;
}

// ============ launch ============
extern "C" void kernel_launch(void* const* d_in, const int* in_sizes, int n_in,
                              void* d_out, int out_size, void* d_ws, size_t ws_size,
                              hipStream_t stream) {
    const float* node_feats = (const float*)d_in[0];
    const float* W_fc       = (const float*)d_in[1];
    const float* attn_l     = (const float*)d_in[2];
    const float* attn_r     = (const float*)d_in[3];
    const float* gat_res_w  = (const float*)d_in[4];
    const float* gat_bias   = (const float*)d_in[5];
    const float* conv_w     = (const float*)d_in[6];
    const float* conv_b     = (const float*)d_in[7];
    const float* res_w      = (const float*)d_in[8];
    const float* res_b      = (const float*)d_in[9];
    const float* bn_gamma   = (const float*)d_in[10];
    const float* bn_beta    = (const float*)d_in[11];
    const int*   src        = (const int*)d_in[12];
    const int*   dst        = (const int*)d_in[13];

    const int N = in_sizes[0] / IN_F;
    const int E = in_sizes[12];
    const int Mtiles = (N + 127) / 128;
    const int nb = (N + 255) / 256;

    char* ws = (char*)d_ws;
    size_t off = 0;
    auto alloc = [&](size_t bytes) -> void* {
        void* p = (void*)(ws + off);
        off += (bytes + 255) & ~(size_t)255;
        return p;
    };

    // --- zero zone ---
    int*   degree  = (int*)alloc((size_t)N * 4);
    float* bnsum   = (float*)alloc(64 * 4);
    float* bnsumsq = (float*)alloc(64 * 4);
    size_t zero_bytes = off;
    // --- rest ---
    int*            rank      = (int*)alloc((size_t)E * 4);
    int*            excl      = (int*)alloc((size_t)N * 4);
    int*            blocksum  = (int*)alloc(256 * 4);
    int*            base      = (int*)alloc(256 * 4);
    uint4*          es_sorted = (uint4*)alloc((size_t)E * 16);
    unsigned short* Btg       = (unsigned short*)alloc((size_t)576 * IN_F * 2);
    unsigned char*  Hh8       = (unsigned char*)alloc((size_t)N * 256);
    unsigned short* Hrest     = (unsigned short*)alloc((size_t)N * RESTC * 2);
    float*          el        = (float*)alloc((size_t)N * 4 * 4);
    float*          er        = (float*)alloc((size_t)N * 4 * 4);
    float*          y         = (float*)alloc((size_t)N * OUTD * 4);
    (void)ws_size; (void)n_in; (void)out_size;

    hipMemsetAsync(d_ws, 0, zero_bytes, stream);

    // 0. pack B weights -> bf16 k-contig
    k0_pack<<<(576 * 128 + 255) / 256, 256, 0, stream>>>(W_fc, gat_res_w, res_w, Btg);
    // 1. MFMA GEMM (m-loop over 9 n-tiles) + histogram + el/er
    k1_gemm<<<Mtiles + HIST_BLOCKS, 256, 0, stream>>>(node_feats, Btg, attn_l, attn_r,
                                                      dst, degree, rank, Hh8, Hrest,
                                                      el, er, N, E, Mtiles);
    // 2. scan
    scanA_kernel<<<nb, 256, 0, stream>>>(degree, excl, blocksum, N);
    scanB_kernel<<<1, 256, 0, stream>>>(blocksum, base, nb);
    // 3. scatter + score compute
    scatter_kernel<<<(E + 255) / 256, 256, 0, stream>>>(src, dst, rank, excl, base,
                                                        el, er, es_sorted, E);
    // 4. aggregation + epilogue
    agg_kernel<<<(N + 3) / 4, 256, 0, stream>>>(Hh8, Hrest, excl, base, es_sorted,
                                                gat_bias, conv_w, conv_b, res_b, y, N, E);
    // 5. BN
    bn_partial_kernel<<<512, 256, 0, stream>>>(y, bnsum, bnsumsq, N * OUTD);
    norm_kernel<<<(N * OUTD / 4 + 255) / 256, 256, 0, stream>>>(y, bnsum, bnsumsq,
                                                                bn_gamma, bn_beta, (float*)d_out,
                                                                N * OUTD / 4, 1.f / (float)N);
}